// Round 15
// baseline (296.207 us; speedup 1.0000x reference)
//
#include <hip/hip_runtime.h>
#include <hip/hip_bf16.h>

typedef __hip_bfloat16 bf16;

static __device__ __forceinline__ float us2f(unsigned short u) {
    union { unsigned int i; float f; } c; c.i = ((unsigned int)u) << 16; return c.f;
}
static __device__ __forceinline__ unsigned short f2us(float f) {
    union { float f; unsigned int i; } c; c.f = f;
    unsigned int r = c.i + 0x7FFF + ((c.i >> 16) & 1);   // round-to-nearest-even
    return (unsigned short)(r >> 16);
}

// wave-0 probe: is the float input stored as f32 (vs bf16)? (see r1 analysis)
static __device__ __forceinline__ int probe_isf32(const unsigned short* xr, int* sflag) {
    int tid = threadIdx.x;
    if (tid < 64) {
        int bad = 0;
        for (int i = tid; i < 1024; i += 64) {
            int ex = (xr[2 * i] >> 7) & 0xFF;
            if (ex < 110 || ex > 135) bad++;
        }
#pragma unroll
        for (int m = 32; m >= 1; m >>= 1) bad += __shfl_xor(bad, m);
        if (tid == 0) *sflag = (bad > 256) ? 1 : 0;
    }
    __syncthreads();
    return *sflag;
}

static __device__ __forceinline__ int ld_edge(const int* er, size_t i, int idx64) {
    return idx64 ? er[2 * i] : er[i];
}

// ---------------- canonicalization + Wcat pack + bcur zero (fused) ----------------

struct CvtArgs { const void* p[19]; int sz[19]; };

static __device__ __forceinline__ float cvt_elem(const void* p, int off, int isf32) {
    return isf32 ? ((const float*)p)[off] : __bfloat162float(((const bf16*)p)[off]);
}

// blocks 0..nbconv-1: convert all float inputs to f32 canon.
// block nbconv: build Wcat[32][32] + bcat from raw inputs, and zero bcur.
__global__ __launch_bounds__(256) void k_convert(CvtArgs a, float* __restrict__ dst, int total,
                                                 int nbconv, float* __restrict__ Wcat,
                                                 float* __restrict__ bcat, int* __restrict__ bcur) {
    __shared__ int sflag;
    int isf32 = probe_isf32((const unsigned short*)a.p[0], &sflag);
    int tid = threadIdx.x;
    if ((int)blockIdx.x == nbconv) {
        // Wq=p[11] bq=p[12] Wk=p[13] bk=p[14] Wv=p[15] bv=p[16] Wsk=p[17] bsk=p[18]
#pragma unroll
        for (int t4 = 0; t4 < 4; ++t4) {
            int idx = t4 * 256 + tid;           // 0..1023
            int c = idx & 31, g = c >> 3, cc = c & 7, kk = idx >> 5;
            const void* Wg = (g == 0) ? a.p[11] : (g == 1) ? a.p[17] : (g == 2) ? a.p[13] : a.p[15];
            Wcat[idx] = (cc < 7) ? cvt_elem(Wg, kk * 7 + cc, isf32) : 0.f;
        }
        if (tid < 32) {
            int g = tid >> 3, cc = tid & 7;
            const void* Bg = (g == 0) ? a.p[12] : (g == 1) ? a.p[18] : (g == 2) ? a.p[14] : a.p[16];
            bcat[tid] = (cc < 7) ? cvt_elem(Bg, cc, isf32) : 0.f;
        }
        bcur[tid] = 0;
        return;
    }
    int t = blockIdx.x * 256 + tid;
    if (t >= total) return;
    int base = 0, seg = -1, off = 0;
#pragma unroll
    for (int i = 0; i < 19; i++) {
        if (seg < 0 && t < base + a.sz[i]) { seg = i; off = t - base; }
        base += a.sz[i];
    }
    dst[t] = cvt_elem(a.p[seg], off, isf32);
}

// ---------------- bucketed CSR build (fixed-capacity buckets; packed bkt) ----------------
// bucket b = dst >> 10; bkt entry = (src << 10) | (dst & 1023)  [src <= 2^18, so 28 bits]

__global__ __launch_bounds__(1024) void k_bscatter(const int* __restrict__ er,
                                                   int* __restrict__ bcur, int* __restrict__ bkt,
                                                   int E, int NB, int C) {
    __shared__ int cnt[256];
    __shared__ int res[256];
    __shared__ int sflag;
    int tid = threadIdx.x;
    if (tid < 64) {
        int lim = (E < 1024) ? E : 1024;
        int nz = 0;
        for (int i = tid; i < lim; i += 64) if (er[2 * i + 1] != 0) nz++;
#pragma unroll
        for (int m = 32; m >= 1; m >>= 1) nz += __shfl_xor(nz, m);
        if (tid == 0) sflag = (nz < ((E < 1024 ? E : 1024) >> 1)) ? 1 : 0;
    }
    if (tid < 256) cnt[tid] = 0;
    __syncthreads();
    int idx64 = sflag;
    int base = blockIdx.x * 4096 + tid;
    int pk[4], bv[4];
    bool val[4];
#pragma unroll
    for (int k = 0; k < 4; ++k) {
        int e = base + k * 1024;
        val[k] = (e < E);
        if (val[k]) {
            int s = ld_edge(er, (size_t)e, idx64);
            int d = ld_edge(er, (size_t)E + e, idx64);
            bv[k] = d >> 10;
            pk[k] = (s << 10) | (d & 1023);
            atomicAdd(&cnt[bv[k]], 1);
        }
    }
    __syncthreads();
    if (tid < NB) {
        int c = cnt[tid];
        res[tid] = c ? atomicAdd(&bcur[tid], c) : 0;
        cnt[tid] = 0;
    }
    __syncthreads();
#pragma unroll
    for (int k = 0; k < 4; ++k) {
        if (val[k]) {
            int r = res[bv[k]] + atomicAdd(&cnt[bv[k]], 1);
            if (r < C) bkt[(size_t)bv[k] * C + r] = pk[k];
        }
    }
}

// per bucket: indeg count + scan -> off2 (start,end); scatter src -> bucket-strided csr
__global__ __launch_bounds__(1024) void k_bbuild(const int* __restrict__ bkt, const int* __restrict__ bcur,
                                                 int2* __restrict__ off2, int* __restrict__ csr, int N, int C) {
    __shared__ int sm[1024];
    int b = blockIdx.x, tid = threadIdx.x;
    size_t base = (size_t)b * C;
    int m = bcur[b]; if (m > C) m = C;
    sm[tid] = 0;
    __syncthreads();
    const int* bp = bkt + base;
    for (int i = tid; i < m; i += 1024) atomicAdd(&sm[bp[i] & 1023], 1);
    __syncthreads();
    int v = sm[tid];
    for (int d = 1; d < 1024; d <<= 1) {
        int t = (tid >= d) ? sm[tid - d] : 0;
        __syncthreads();
        sm[tid] += t;
        __syncthreads();
    }
    int excl = sm[tid] - v;
    int node = (b << 10) + tid;
    if (node < N) off2[node] = make_int2((int)base + excl, (int)base + excl + v);
    __syncthreads();
    sm[tid] = excl;
    __syncthreads();
    for (int i = tid; i < m; i += 1024) {
        int p = bp[i];
        int r = atomicAdd(&sm[p & 1023], 1);
        csr[base + r] = p >> 10;
    }
}

// ---------------- Layer 1: GATConv(3, 16, heads=4) ----------------

__global__ __launch_bounds__(256) void k_l1_transform(const float* __restrict__ x, const float* __restrict__ W1,
                                                      const float* __restrict__ att_s, const float* __restrict__ att_d,
                                                      float4* __restrict__ x4, float* __restrict__ as1,
                                                      float* __restrict__ ad1, int N) {
    int tid = threadIdx.x;
    int node = blockIdx.x * 4 + (tid >> 6);
    if (node >= N) return;
    int lane = tid & 63;
    float x0 = x[node * 3 + 0];
    float x1 = x[node * 3 + 1];
    float x2 = x[node * 3 + 2];
    float h = x0 * W1[lane] + x1 * W1[64 + lane] + x2 * W1[128 + lane];
    if (lane == 0) x4[node] = make_float4(x0, x1, x2, 0.f);
    float ts = h * att_s[lane];
    float td = h * att_d[lane];
    for (int m = 8; m >= 1; m >>= 1) { ts += __shfl_xor(ts, m); td += __shfl_xor(td, m); }
    if ((lane & 15) == 0) {
        as1[node * 4 + (lane >> 4)] = ts;
        ad1[node * 4 + (lane >> 4)] = td;
    }
}

// Edge-parallel: 16 lanes per node; accumulate per-head weighted x-3vec + denom, butterfly-reduce.
__global__ __launch_bounds__(256) void k_l1_agg(const float4* __restrict__ x4, const float4* __restrict__ as4,
                                                const float4* __restrict__ ad4p, const int2* __restrict__ off2,
                                                const int* __restrict__ csr, const float* __restrict__ W1,
                                                const float* __restrict__ b1,
                                                float* __restrict__ x1, int N) {
    int tid = threadIdx.x;
    int node = blockIdx.x * 16 + (tid >> 4);
    if (node >= N) return;
    int sl = tid & 15;
    int lane = tid & 63;
    int lb = lane & 48;

    float4 ad = ad4p[node];
    int2 ee = off2[node];
    int e0 = ee.x, e1 = ee.y;

    float v[16];
#pragma unroll
    for (int i = 0; i < 16; ++i) v[i] = 0.f;

    for (int jj = e0 + sl; jj < e1; jj += 16) {
        int s = csr[jj];
        float4 a = as4[s];
        float4 xv = x4[s];
        float z0 = a.x + ad.x, z1 = a.y + ad.y, z2 = a.z + ad.z, z3 = a.w + ad.w;
        z0 = (z0 > 0.f) ? z0 : 0.2f * z0;
        z1 = (z1 > 0.f) ? z1 : 0.2f * z1;
        z2 = (z2 > 0.f) ? z2 : 0.2f * z2;
        z3 = (z3 > 0.f) ? z3 : 0.2f * z3;
        float w0 = __expf(z0), w1 = __expf(z1), w2 = __expf(z2), w3 = __expf(z3);
        v[0] += w0 * xv.x; v[1] += w0 * xv.y; v[2]  += w0 * xv.z; v[3]  += w0;
        v[4] += w1 * xv.x; v[5] += w1 * xv.y; v[6]  += w1 * xv.z; v[7]  += w1;
        v[8] += w2 * xv.x; v[9] += w2 * xv.y; v[10] += w2 * xv.z; v[11] += w2;
        v[12] += w3 * xv.x; v[13] += w3 * xv.y; v[14] += w3 * xv.z; v[15] += w3;
    }

#pragma unroll
    for (int d = 8; d >= 1; d >>= 1) {
#pragma unroll
        for (int i = 0; i < 16; ++i) {
            if (i < d) {
                float a = v[i], b = v[i + d];
                float send = (sl & d) ? a : b;
                float recv = __shfl_xor(send, d);
                v[i] = ((sl & d) ? b : a) + recv;
            }
        }
    }
    float r = v[0];

    float agx[4], agy[4], agz[4], dn[4];
#pragma unroll
    for (int h = 0; h < 4; ++h) {
        agx[h] = __shfl(r, lb + 4 * h + 0);
        agy[h] = __shfl(r, lb + 4 * h + 1);
        agz[h] = __shfl(r, lb + 4 * h + 2);
        dn[h]  = __shfl(r, lb + 4 * h + 3);
    }

    {
        float4 a = as4[node];
        float4 xv = x4[node];
        float z0 = a.x + ad.x, z1 = a.y + ad.y, z2 = a.z + ad.z, z3 = a.w + ad.w;
        z0 = (z0 > 0.f) ? z0 : 0.2f * z0;
        z1 = (z1 > 0.f) ? z1 : 0.2f * z1;
        z2 = (z2 > 0.f) ? z2 : 0.2f * z2;
        z3 = (z3 > 0.f) ? z3 : 0.2f * z3;
        float w0 = __expf(z0), w1 = __expf(z1), w2 = __expf(z2), w3 = __expf(z3);
        agx[0] += w0 * xv.x; agy[0] += w0 * xv.y; agz[0] += w0 * xv.z; dn[0] += w0;
        agx[1] += w1 * xv.x; agy[1] += w1 * xv.y; agz[1] += w1 * xv.z; dn[1] += w1;
        agx[2] += w2 * xv.x; agy[2] += w2 * xv.y; agz[2] += w2 * xv.z; dn[2] += w2;
        agx[3] += w3 * xv.x; agy[3] += w3 * xv.y; agz[3] += w3 * xv.z; dn[3] += w3;
    }

#pragma unroll
    for (int h = 0; h < 4; ++h) {
        int j = h * 16 + sl;
        float inv = 1.f / (dn[h] + 1e-16f);
        float o = (agx[h] * W1[j] + agy[h] * W1[64 + j] + agz[h] * W1[128 + j]) * inv + b1[j];
        x1[(size_t)node * 64 + j] = (o > 0.f) ? o : 0.f;
    }
}

// ---------------- Layer 2: GATv2Conv(64, 16, heads=2) ----------------

// 64 nodes per 256-thread block; thread = 4-node x 4-col register tile of [hl|hr].
// k4 loop unroll capped at 2: full unroll hoisted 64 weight float4s -> 252 VGPR, 8.9% occupancy (r10).
__global__ __launch_bounds__(256) void k_l2_transform(const float* __restrict__ x1,
                                                      const float* __restrict__ W2l, const float* __restrict__ b2l,
                                                      const float* __restrict__ W2r, const float* __restrict__ b2r,
                                                      unsigned short* __restrict__ hlb, float* __restrict__ hr, int N) {
    __shared__ float xs[64 * 68];   // row stride 68: per-wave broadcast rows hit banks {0,4,8,12}
    int t = threadIdx.x;
    int node0 = blockIdx.x * 64;
    int nrem = N - node0; if (nrem > 64) nrem = 64;
    const float4* xg = (const float4*)x1;
#pragma unroll
    for (int it = 0; it < 4; ++it) {
        int id = it * 256 + t;
        int row = id >> 4, c4 = id & 15;
        float4 v = make_float4(0.f, 0.f, 0.f, 0.f);
        if (row < nrem) v = xg[(size_t)(node0 + row) * 16 + c4];
        *(float4*)&xs[row * 68 + c4 * 4] = v;
    }
    __syncthreads();
    int nt = t >> 4;
    int jt = t & 15;
    int jq = jt & 7;
    int jc = jq * 4;
    const float4* W4 = (const float4*)((jt < 8) ? W2l : W2r);
    const float4* B4 = (const float4*)((jt < 8) ? b2l : b2r);
    float4 bb = B4[jq];
    float4 acc[4];
#pragma unroll
    for (int i = 0; i < 4; ++i) acc[i] = bb;
#pragma unroll 2
    for (int k4 = 0; k4 < 16; ++k4) {
        float4 w0 = W4[(k4 * 4 + 0) * 8 + jq];
        float4 w1 = W4[(k4 * 4 + 1) * 8 + jq];
        float4 w2 = W4[(k4 * 4 + 2) * 8 + jq];
        float4 w3 = W4[(k4 * 4 + 3) * 8 + jq];
#pragma unroll
        for (int i = 0; i < 4; ++i) {
            float4 xv = *(const float4*)&xs[(nt + i * 16) * 68 + k4 * 4];
            acc[i].x += xv.x * w0.x + xv.y * w1.x + xv.z * w2.x + xv.w * w3.x;
            acc[i].y += xv.x * w0.y + xv.y * w1.y + xv.z * w2.y + xv.w * w3.y;
            acc[i].z += xv.x * w0.z + xv.y * w1.z + xv.z * w2.z + xv.w * w3.z;
            acc[i].w += xv.x * w0.w + xv.y * w1.w + xv.z * w2.w + xv.w * w3.w;
        }
    }
#pragma unroll
    for (int i = 0; i < 4; ++i) {
        int row = nt + i * 16;
        if (row < nrem) {
            size_t node = node0 + row;
            if (jt < 8) {
                uint2 p;
                p.x = (unsigned)f2us(acc[i].x) | ((unsigned)f2us(acc[i].y) << 16);
                p.y = (unsigned)f2us(acc[i].z) | ((unsigned)f2us(acc[i].w) << 16);
                *(uint2*)&hlb[node * 32 + jc] = p;
            } else {
                *(float4*)&hr[node * 32 + jc] = acc[i];
            }
        }
    }
}

// Edge-parallel: 16 lanes per node, lane = edge slot. Full 64B hl row per edge (4x uint4),
// both head logits in-register; one butterfly per node. Epilogue: fused layer-3 transform —
// lane sl holds x2 channels {sl, 16+sl}; 32-col partials vs Wcat, 32->2 butterfly, store QS/KVb.
__global__ __launch_bounds__(256) void k_l2_agg(const unsigned short* __restrict__ hlb, const float* __restrict__ hr,
                                                const float* __restrict__ att2, const float* __restrict__ b2,
                                                const int2* __restrict__ off2, const int* __restrict__ csr,
                                                const float4* __restrict__ Wc4, const float* __restrict__ bcat,
                                                float* __restrict__ QS, unsigned short* __restrict__ KVb, int N) {
    int tid = threadIdx.x;
    int node = blockIdx.x * 16 + (tid >> 4);
    if (node >= N) return;
    int sl = tid & 15;

    float hrd[32];
    {
        const float4* hr4 = (const float4*)(hr + (size_t)node * 32);
#pragma unroll
        for (int q = 0; q < 8; ++q) {
            float4 v = hr4[q];
            hrd[4 * q + 0] = v.x; hrd[4 * q + 1] = v.y;
            hrd[4 * q + 2] = v.z; hrd[4 * q + 3] = v.w;
        }
    }

    float accA[16], accB[16];
#pragma unroll
    for (int i = 0; i < 16; ++i) { accA[i] = 0.f; accB[i] = 0.f; }
    float den0 = 0.f, den1 = 0.f;

    int2 ee = off2[node];
    int e0 = ee.x, e1 = ee.y;
    for (int jj = e0 + sl; jj < e1; jj += 16) {
        int s = csr[jj];
        const uint4* hp = (const uint4*)(hlb + (size_t)s * 32);
        uint4 u0 = hp[0], u1 = hp[1], u2 = hp[2], u3 = hp[3];
        unsigned int uu[16] = {u0.x, u0.y, u0.z, u0.w, u1.x, u1.y, u1.z, u1.w,
                               u2.x, u2.y, u2.z, u2.w, u3.x, u3.y, u3.z, u3.w};
        float t0 = 0.f, t1 = 0.f;
#pragma unroll
        for (int q = 0; q < 8; ++q) {
            float lo = __uint_as_float(uu[q] << 16);
            float hi = __uint_as_float(uu[q] & 0xFFFF0000u);
            float el = lo + hrd[2 * q];     el = fmaxf(el, 0.2f * el);
            float eh = hi + hrd[2 * q + 1]; eh = fmaxf(eh, 0.2f * eh);
            t0 += att2[2 * q] * el + att2[2 * q + 1] * eh;
        }
#pragma unroll
        for (int q = 8; q < 16; ++q) {
            float lo = __uint_as_float(uu[q] << 16);
            float hi = __uint_as_float(uu[q] & 0xFFFF0000u);
            float el = lo + hrd[2 * q];     el = fmaxf(el, 0.2f * el);
            float eh = hi + hrd[2 * q + 1]; eh = fmaxf(eh, 0.2f * eh);
            t1 += att2[2 * q] * el + att2[2 * q + 1] * eh;
        }
        float w0 = __expf(t0), w1 = __expf(t1);
        den0 += w0; den1 += w1;
#pragma unroll
        for (int q = 0; q < 8; ++q) {
            accA[2 * q]     += w0 * __uint_as_float(uu[q] << 16);
            accA[2 * q + 1] += w0 * __uint_as_float(uu[q] & 0xFFFF0000u);
        }
#pragma unroll
        for (int q = 8; q < 16; ++q) {
            accB[2 * (q - 8)]     += w1 * __uint_as_float(uu[q] << 16);
            accB[2 * (q - 8) + 1] += w1 * __uint_as_float(uu[q] & 0xFFFF0000u);
        }
    }

#pragma unroll
    for (int d = 8; d >= 1; d >>= 1) {
#pragma unroll
        for (int i = 0; i < 16; ++i) {
            if (i < d) {
                { float a = accA[i], b = accA[i + d];
                  float send = (sl & d) ? a : b;
                  float recv = __shfl_xor(send, d);
                  accA[i] = ((sl & d) ? b : a) + recv; }
                { float a = accB[i], b = accB[i + d];
                  float send = (sl & d) ? a : b;
                  float recv = __shfl_xor(send, d);
                  accB[i] = ((sl & d) ? b : a) + recv; }
            }
        }
        den0 += __shfl_xor(den0, d);
        den1 += __shfl_xor(den1, d);
    }
    float sumA = accA[0];
    float sumB = accB[0];

    // self-loop (cooperative: lane sl holds channels sl and 16+sl)
    float hr0 = hrd[0]; // NOTE: hrd indexed per-lane below instead
    hr0 = hr[(size_t)node * 32 + sl];
    float hr1 = hr[(size_t)node * 32 + 16 + sl];
    float hl0 = us2f(hlb[(size_t)node * 32 + sl]);
    float hl1 = us2f(hlb[(size_t)node * 32 + 16 + sl]);
    float ea = hl0 + hr0; ea = fmaxf(ea, 0.2f * ea);
    float eb = hl1 + hr1; eb = fmaxf(eb, 0.2f * eb);
    float p0 = att2[sl] * ea;
    float p1 = att2[16 + sl] * eb;
    p0 += __shfl_xor(p0, 1); p0 += __shfl_xor(p0, 2); p0 += __shfl_xor(p0, 4); p0 += __shfl_xor(p0, 8);
    p1 += __shfl_xor(p1, 1); p1 += __shfl_xor(p1, 2); p1 += __shfl_xor(p1, 4); p1 += __shfl_xor(p1, 8);
    float w0 = __expf(p0), w1 = __expf(p1);
    sumA += w0 * hl0; den0 += w0;
    sumB += w1 * hl1; den1 += w1;

    float xa = sumA / (den0 + 1e-16f) + b2[sl];        // x2 channel sl
    float xb = sumB / (den1 + 1e-16f) + b2[16 + sl];   // x2 channel 16+sl

    // ---- fused layer-3 transform: partials for all 32 Wcat cols, 32->2 butterfly ----
    float v2[32];
    {
        const float4* ra = Wc4 + sl * 8;          // Wcat row sl
        const float4* rb = Wc4 + (16 + sl) * 8;   // Wcat row 16+sl
#pragma unroll
        for (int q = 0; q < 8; ++q) {
            float4 wa = ra[q], wb = rb[q];
            v2[4 * q + 0] = xa * wa.x + xb * wb.x;
            v2[4 * q + 1] = xa * wa.y + xb * wb.y;
            v2[4 * q + 2] = xa * wa.z + xb * wb.z;
            v2[4 * q + 3] = xa * wa.w + xb * wb.w;
        }
    }
#pragma unroll
    for (int d = 8; d >= 1; d >>= 1) {
#pragma unroll
        for (int i = 0; i < 32; ++i) {
            if (i < 2 * d) {
                float a = v2[i], b = v2[i + 2 * d];
                float send = (sl & d) ? a : b;
                float recv = __shfl_xor(send, d);
                v2[i] = ((sl & d) ? b : a) + recv;
            }
        }
    }
    // lane sl holds cols j0=2sl, j1=2sl+1
    float o0 = v2[0] + bcat[2 * sl];
    float o1 = v2[1] + bcat[2 * sl + 1];
    if (sl < 8) {
        *(float2*)&QS[(size_t)node * 16 + 2 * sl] = make_float2(o0, o1);
    } else {
        unsigned int p = (unsigned)f2us(o0) | ((unsigned)f2us(o1) << 16);
        *(unsigned int*)&KVb[(size_t)node * 16 + (2 * sl - 16)] = p;
    }
}

// ---------------- Layer 3 aggregate ----------------

// Edge-parallel: 8 lanes per node, lane = edge slot; bf16 K|V row per edge (2x uint4 = 32B,
// KVb table 3.2MB -> per-XCD L2-resident); dot in f32; 8 values (7 acc + den) butterflied.
__global__ __launch_bounds__(256) void k_l3_agg(const float* __restrict__ QS, const unsigned short* __restrict__ KVb,
                                                const int2* __restrict__ off2, const int* __restrict__ csr,
                                                float* __restrict__ out, int N) {
    int tid = threadIdx.x;
    int node = blockIdx.x * 32 + (tid >> 3);
    if (node >= N) return;
    int sl = tid & 7;
    int lane = tid & 63;
    const float scale = 0.3779644730092272f;  // 1/sqrt(7)
    const float4* q4 = (const float4*)(QS + (size_t)node * 16);
    float4 qa = q4[0], qb = q4[1];
    qa.x *= scale; qa.y *= scale; qa.z *= scale; qa.w *= scale;
    qb.x *= scale; qb.y *= scale; qb.z *= scale; qb.w = 0.f;

    float v[8];
#pragma unroll
    for (int i = 0; i < 8; ++i) v[i] = 0.f;

    int2 ee = off2[node];
    int e0 = ee.x, e1 = ee.y;
    for (int jj = e0 + sl; jj < e1; jj += 8) {
        int s = csr[jj];
        const uint4* kp = (const uint4*)(KVb + (size_t)s * 16);
        uint4 uk = kp[0], uv = kp[1];
        float k0 = __uint_as_float(uk.x << 16),        k1 = __uint_as_float(uk.x & 0xFFFF0000u);
        float k2 = __uint_as_float(uk.y << 16),        k3 = __uint_as_float(uk.y & 0xFFFF0000u);
        float k4 = __uint_as_float(uk.z << 16),        k5 = __uint_as_float(uk.z & 0xFFFF0000u);
        float k6 = __uint_as_float(uk.w << 16);
        float t = qa.x * k0 + qa.y * k1 + qa.z * k2 + qa.w * k3
                + qb.x * k4 + qb.y * k5 + qb.z * k6;
        float w = __expf(t);
        v[0] += w * __uint_as_float(uv.x << 16);
        v[1] += w * __uint_as_float(uv.x & 0xFFFF0000u);
        v[2] += w * __uint_as_float(uv.y << 16);
        v[3] += w * __uint_as_float(uv.y & 0xFFFF0000u);
        v[4] += w * __uint_as_float(uv.z << 16);
        v[5] += w * __uint_as_float(uv.z & 0xFFFF0000u);
        v[6] += w * __uint_as_float(uv.w << 16);
        v[7] += w;
    }
#pragma unroll
    for (int d = 4; d >= 1; d >>= 1) {
#pragma unroll
        for (int i = 0; i < 8; ++i) {
            if (i < d) {
                float a = v[i], b = v[i + d];
                float send = (sl & d) ? a : b;
                float recv = __shfl_xor(send, d);
                v[i] = ((sl & d) ? b : a) + recv;
            }
        }
    }
    float r = v[0];
    float den = __shfl(r, (lane & 56) + 7);
    if (sl < 7) out[(size_t)node * 7 + sl] = r / (den + 1e-16f)
                                             + QS[(size_t)node * 16 + 8 + sl];
}

// ---------------- launcher ----------------

extern "C" void kernel_launch(void* const* d_in, const int* in_sizes, int n_in,
                              void* d_out, int out_size, void* d_ws, size_t ws_size,
                              hipStream_t stream) {
    const int* ei = (const int*)d_in[1];
    float* out = (float*)d_out;

    int N = in_sizes[0] / 3;
    int E = in_sizes[1] / 2;
    int NB = (N + 1023) >> 10;   // assumed <= 256 (N <= 262144)
    int C = (E + NB - 1) / NB + 4096;   // fixed bucket capacity (mean + huge slack for random dst)

    char* ws = (char*)d_ws;
    size_t o = 0;
    auto take = [&](size_t bytes) -> char* {
        char* p = ws + o;
        o = (o + bytes + 255) & ~(size_t)255;
        return p;
    };
    int total_f = 0;
    for (int i = 0; i < 20; ++i) if (i != 1) total_f += in_sizes[i];
    float* canon   = (float*)take((size_t)total_f * 4);
    float* Wcat    = (float*)take(32 * 32 * 4);
    float* bcat    = (float*)take(32 * 4);
    int2*  off2    = (int2*)take((size_t)N * 8);
    int*   bcur    = (int*)take(256 * 4);
    int*   csr     = (int*)take((size_t)NB * C * 4);
    float* bufA    = (float*)take((size_t)N * 64 * 4);  // x4 -> hlb|hr
    float* as1     = (float*)take((size_t)N * 4 * 4);
    float* ad1     = (float*)take((size_t)N * 4 * 4);
    float* bufB    = (float*)take((size_t)N * 64 * 4);  // bkt -> x1 -> QS|KVb
    (void)ws_size; (void)n_in; (void)out_size;

    CvtArgs ca;
    const float* cp[20];
    {
        int off_ = 0, k = 0;
        for (int i = 0; i < 20; ++i) {
            if (i == 1) { cp[i] = nullptr; continue; }
            ca.p[k] = d_in[i];
            ca.sz[k] = in_sizes[i];
            cp[i] = canon + off_;
            off_ += in_sizes[i];
            ++k;
        }
    }

    int nbconv = (total_f + 255) / 256;
    k_convert<<<nbconv + 1, 256, 0, stream>>>(ca, canon, total_f, nbconv, Wcat, bcat, bcur);

    // bkt aliases bufB (NB*C*4 B ~= 8 MB <= N*256 B); x1 written only after k_bbuild
    int* bkt = (int*)bufB;
    int gb = (E + 4095) / 4096;
    k_bscatter<<<gb, 1024, 0, stream>>>(ei, bcur, bkt, E, NB, C);
    k_bbuild<<<NB, 1024, 0, stream>>>(bkt, bcur, off2, csr, N, C);

    float4* x4 = (float4*)bufA;                                  // N*16B = 1.6 MB, L2-resident
    k_l1_transform<<<(N + 3) / 4, 256, 0, stream>>>(cp[0], cp[2], cp[3], cp[4], x4, as1, ad1, N);
    float* x1 = bufB;
    k_l1_agg<<<(N + 15) / 16, 256, 0, stream>>>(x4, (const float4*)as1, (const float4*)ad1,
                                                off2, csr, cp[2], cp[5], x1, N);

    unsigned short* hlb = (unsigned short*)bufA;                 // N*32 bf16 = 6.4 MB
    float* hr = bufA + (size_t)N * 16;
    k_l2_transform<<<(N + 63) / 64, 256, 0, stream>>>(x1, cp[6], cp[7], cp[8], cp[9], hlb, hr, N);

    // QS|KVb go into bufB (x1 is dead after k_l2_transform; hlb/hr stay live in bufA)
    float* QS = bufB;                                            // N*16 floats
    unsigned short* KVb = (unsigned short*)(bufB + (size_t)N * 16);  // N*16 bf16 = 3.2 MB (L2-resident)
    k_l2_agg<<<(N + 15) / 16, 256, 0, stream>>>(hlb, hr, cp[10], cp[11], off2, csr,
                                                (const float4*)Wcat, bcat, QS, KVb, N);

    k_l3_agg<<<(N + 31) / 32, 256, 0, stream>>>(QS, KVb, off2, csr, out, N);
}

// Round 16
// 273.763 us; speedup vs baseline: 1.0820x; 1.0820x over previous
//
#include <hip/hip_runtime.h>
#include <hip/hip_bf16.h>

typedef __hip_bfloat16 bf16;

static __device__ __forceinline__ float us2f(unsigned short u) {
    union { unsigned int i; float f; } c; c.i = ((unsigned int)u) << 16; return c.f;
}
static __device__ __forceinline__ unsigned short f2us(float f) {
    union { float f; unsigned int i; } c; c.f = f;
    unsigned int r = c.i + 0x7FFF + ((c.i >> 16) & 1);   // round-to-nearest-even
    return (unsigned short)(r >> 16);
}

// wave-0 probe: is the float input stored as f32 (vs bf16)? (see r1 analysis)
static __device__ __forceinline__ int probe_isf32(const unsigned short* xr, int* sflag) {
    int tid = threadIdx.x;
    if (tid < 64) {
        int bad = 0;
        for (int i = tid; i < 1024; i += 64) {
            int ex = (xr[2 * i] >> 7) & 0xFF;
            if (ex < 110 || ex > 135) bad++;
        }
#pragma unroll
        for (int m = 32; m >= 1; m >>= 1) bad += __shfl_xor(bad, m);
        if (tid == 0) *sflag = (bad > 256) ? 1 : 0;
    }
    __syncthreads();
    return *sflag;
}

static __device__ __forceinline__ int ld_edge(const int* er, size_t i, int idx64) {
    return idx64 ? er[2 * i] : er[i];
}

// ---------------- canonicalization + Wcat pack + bcur zero (fused) ----------------

struct CvtArgs { const void* p[19]; int sz[19]; };

static __device__ __forceinline__ float cvt_elem(const void* p, int off, int isf32) {
    return isf32 ? ((const float*)p)[off] : __bfloat162float(((const bf16*)p)[off]);
}

// blocks 0..nbconv-1: convert all float inputs to f32 canon.
// block nbconv: build Wcat[32][32] + bcat from raw inputs, and zero bcur.
__global__ __launch_bounds__(256) void k_convert(CvtArgs a, float* __restrict__ dst, int total,
                                                 int nbconv, float* __restrict__ Wcat,
                                                 float* __restrict__ bcat, int* __restrict__ bcur) {
    __shared__ int sflag;
    int isf32 = probe_isf32((const unsigned short*)a.p[0], &sflag);
    int tid = threadIdx.x;
    if ((int)blockIdx.x == nbconv) {
        // Wq=p[11] bq=p[12] Wk=p[13] bk=p[14] Wv=p[15] bv=p[16] Wsk=p[17] bsk=p[18]
#pragma unroll
        for (int t4 = 0; t4 < 4; ++t4) {
            int idx = t4 * 256 + tid;           // 0..1023
            int c = idx & 31, g = c >> 3, cc = c & 7, kk = idx >> 5;
            const void* Wg = (g == 0) ? a.p[11] : (g == 1) ? a.p[17] : (g == 2) ? a.p[13] : a.p[15];
            Wcat[idx] = (cc < 7) ? cvt_elem(Wg, kk * 7 + cc, isf32) : 0.f;
        }
        if (tid < 32) {
            int g = tid >> 3, cc = tid & 7;
            const void* Bg = (g == 0) ? a.p[12] : (g == 1) ? a.p[18] : (g == 2) ? a.p[14] : a.p[16];
            bcat[tid] = (cc < 7) ? cvt_elem(Bg, cc, isf32) : 0.f;
        }
        bcur[tid] = 0;
        return;
    }
    int t = blockIdx.x * 256 + tid;
    if (t >= total) return;
    int base = 0, seg = -1, off = 0;
#pragma unroll
    for (int i = 0; i < 19; i++) {
        if (seg < 0 && t < base + a.sz[i]) { seg = i; off = t - base; }
        base += a.sz[i];
    }
    dst[t] = cvt_elem(a.p[seg], off, isf32);
}

// ---------------- bucketed CSR build (fixed-capacity buckets; packed bkt) ----------------
// bucket b = dst >> 10; bkt entry = (src << 10) | (dst & 1023)  [src <= 2^18, so 28 bits]

__global__ __launch_bounds__(1024) void k_bscatter(const int* __restrict__ er,
                                                   int* __restrict__ bcur, int* __restrict__ bkt,
                                                   int E, int NB, int C) {
    __shared__ int cnt[256];
    __shared__ int res[256];
    __shared__ int sflag;
    int tid = threadIdx.x;
    if (tid < 64) {
        int lim = (E < 1024) ? E : 1024;
        int nz = 0;
        for (int i = tid; i < lim; i += 64) if (er[2 * i + 1] != 0) nz++;
#pragma unroll
        for (int m = 32; m >= 1; m >>= 1) nz += __shfl_xor(nz, m);
        if (tid == 0) sflag = (nz < ((E < 1024 ? E : 1024) >> 1)) ? 1 : 0;
    }
    if (tid < 256) cnt[tid] = 0;
    __syncthreads();
    int idx64 = sflag;
    int base = blockIdx.x * 4096 + tid;
    int pk[4], bv[4];
    bool val[4];
#pragma unroll
    for (int k = 0; k < 4; ++k) {
        int e = base + k * 1024;
        val[k] = (e < E);
        if (val[k]) {
            int s = ld_edge(er, (size_t)e, idx64);
            int d = ld_edge(er, (size_t)E + e, idx64);
            bv[k] = d >> 10;
            pk[k] = (s << 10) | (d & 1023);
            atomicAdd(&cnt[bv[k]], 1);
        }
    }
    __syncthreads();
    if (tid < NB) {
        int c = cnt[tid];
        res[tid] = c ? atomicAdd(&bcur[tid], c) : 0;
        cnt[tid] = 0;
    }
    __syncthreads();
#pragma unroll
    for (int k = 0; k < 4; ++k) {
        if (val[k]) {
            int r = res[bv[k]] + atomicAdd(&cnt[bv[k]], 1);
            if (r < C) bkt[(size_t)bv[k] * C + r] = pk[k];
        }
    }
}

// per bucket: indeg count + scan -> off2 (start,end); scatter src -> bucket-strided csr
__global__ __launch_bounds__(1024) void k_bbuild(const int* __restrict__ bkt, const int* __restrict__ bcur,
                                                 int2* __restrict__ off2, int* __restrict__ csr, int N, int C) {
    __shared__ int sm[1024];
    int b = blockIdx.x, tid = threadIdx.x;
    size_t base = (size_t)b * C;
    int m = bcur[b]; if (m > C) m = C;
    sm[tid] = 0;
    __syncthreads();
    const int* bp = bkt + base;
    for (int i = tid; i < m; i += 1024) atomicAdd(&sm[bp[i] & 1023], 1);
    __syncthreads();
    int v = sm[tid];
    for (int d = 1; d < 1024; d <<= 1) {
        int t = (tid >= d) ? sm[tid - d] : 0;
        __syncthreads();
        sm[tid] += t;
        __syncthreads();
    }
    int excl = sm[tid] - v;
    int node = (b << 10) + tid;
    if (node < N) off2[node] = make_int2((int)base + excl, (int)base + excl + v);
    __syncthreads();
    sm[tid] = excl;
    __syncthreads();
    for (int i = tid; i < m; i += 1024) {
        int p = bp[i];
        int r = atomicAdd(&sm[p & 1023], 1);
        csr[base + r] = p >> 10;
    }
}

// ---------------- Layer 1: GATConv(3, 16, heads=4) ----------------

__global__ __launch_bounds__(256) void k_l1_transform(const float* __restrict__ x, const float* __restrict__ W1,
                                                      const float* __restrict__ att_s, const float* __restrict__ att_d,
                                                      float4* __restrict__ x4, float* __restrict__ as1,
                                                      float* __restrict__ ad1, int N) {
    int tid = threadIdx.x;
    int node = blockIdx.x * 4 + (tid >> 6);
    if (node >= N) return;
    int lane = tid & 63;
    float x0 = x[node * 3 + 0];
    float x1 = x[node * 3 + 1];
    float x2 = x[node * 3 + 2];
    float h = x0 * W1[lane] + x1 * W1[64 + lane] + x2 * W1[128 + lane];
    if (lane == 0) x4[node] = make_float4(x0, x1, x2, 0.f);
    float ts = h * att_s[lane];
    float td = h * att_d[lane];
    for (int m = 8; m >= 1; m >>= 1) { ts += __shfl_xor(ts, m); td += __shfl_xor(td, m); }
    if ((lane & 15) == 0) {
        as1[node * 4 + (lane >> 4)] = ts;
        ad1[node * 4 + (lane >> 4)] = td;
    }
}

// Edge-parallel: 16 lanes per node; accumulate per-head weighted x-3vec + denom, butterfly-reduce.
__global__ __launch_bounds__(256) void k_l1_agg(const float4* __restrict__ x4, const float4* __restrict__ as4,
                                                const float4* __restrict__ ad4p, const int2* __restrict__ off2,
                                                const int* __restrict__ csr, const float* __restrict__ W1,
                                                const float* __restrict__ b1,
                                                float* __restrict__ x1, int N) {
    int tid = threadIdx.x;
    int node = blockIdx.x * 16 + (tid >> 4);
    if (node >= N) return;
    int sl = tid & 15;
    int lane = tid & 63;
    int lb = lane & 48;

    float4 ad = ad4p[node];
    int2 ee = off2[node];
    int e0 = ee.x, e1 = ee.y;

    float v[16];
#pragma unroll
    for (int i = 0; i < 16; ++i) v[i] = 0.f;

    for (int jj = e0 + sl; jj < e1; jj += 16) {
        int s = csr[jj];
        float4 a = as4[s];
        float4 xv = x4[s];
        float z0 = a.x + ad.x, z1 = a.y + ad.y, z2 = a.z + ad.z, z3 = a.w + ad.w;
        z0 = (z0 > 0.f) ? z0 : 0.2f * z0;
        z1 = (z1 > 0.f) ? z1 : 0.2f * z1;
        z2 = (z2 > 0.f) ? z2 : 0.2f * z2;
        z3 = (z3 > 0.f) ? z3 : 0.2f * z3;
        float w0 = __expf(z0), w1 = __expf(z1), w2 = __expf(z2), w3 = __expf(z3);
        v[0] += w0 * xv.x; v[1] += w0 * xv.y; v[2]  += w0 * xv.z; v[3]  += w0;
        v[4] += w1 * xv.x; v[5] += w1 * xv.y; v[6]  += w1 * xv.z; v[7]  += w1;
        v[8] += w2 * xv.x; v[9] += w2 * xv.y; v[10] += w2 * xv.z; v[11] += w2;
        v[12] += w3 * xv.x; v[13] += w3 * xv.y; v[14] += w3 * xv.z; v[15] += w3;
    }

#pragma unroll
    for (int d = 8; d >= 1; d >>= 1) {
#pragma unroll
        for (int i = 0; i < 16; ++i) {
            if (i < d) {
                float a = v[i], b = v[i + d];
                float send = (sl & d) ? a : b;
                float recv = __shfl_xor(send, d);
                v[i] = ((sl & d) ? b : a) + recv;
            }
        }
    }
    float r = v[0];

    float agx[4], agy[4], agz[4], dn[4];
#pragma unroll
    for (int h = 0; h < 4; ++h) {
        agx[h] = __shfl(r, lb + 4 * h + 0);
        agy[h] = __shfl(r, lb + 4 * h + 1);
        agz[h] = __shfl(r, lb + 4 * h + 2);
        dn[h]  = __shfl(r, lb + 4 * h + 3);
    }

    {
        float4 a = as4[node];
        float4 xv = x4[node];
        float z0 = a.x + ad.x, z1 = a.y + ad.y, z2 = a.z + ad.z, z3 = a.w + ad.w;
        z0 = (z0 > 0.f) ? z0 : 0.2f * z0;
        z1 = (z1 > 0.f) ? z1 : 0.2f * z1;
        z2 = (z2 > 0.f) ? z2 : 0.2f * z2;
        z3 = (z3 > 0.f) ? z3 : 0.2f * z3;
        float w0 = __expf(z0), w1 = __expf(z1), w2 = __expf(z2), w3 = __expf(z3);
        agx[0] += w0 * xv.x; agy[0] += w0 * xv.y; agz[0] += w0 * xv.z; dn[0] += w0;
        agx[1] += w1 * xv.x; agy[1] += w1 * xv.y; agz[1] += w1 * xv.z; dn[1] += w1;
        agx[2] += w2 * xv.x; agy[2] += w2 * xv.y; agz[2] += w2 * xv.z; dn[2] += w2;
        agx[3] += w3 * xv.x; agy[3] += w3 * xv.y; agz[3] += w3 * xv.z; dn[3] += w3;
    }

#pragma unroll
    for (int h = 0; h < 4; ++h) {
        int j = h * 16 + sl;
        float inv = 1.f / (dn[h] + 1e-16f);
        float o = (agx[h] * W1[j] + agy[h] * W1[64 + j] + agz[h] * W1[128 + j]) * inv + b1[j];
        x1[(size_t)node * 64 + j] = (o > 0.f) ? o : 0.f;
    }
}

// ---------------- Layer 2: GATv2Conv(64, 16, heads=2) ----------------

// 64 nodes per 256-thread block; thread = 4-node x 4-col register tile of [hl|hr].
// k4 loop unroll capped at 2: full unroll hoisted 64 weight float4s -> 252 VGPR, 8.9% occupancy (r10).
__global__ __launch_bounds__(256) void k_l2_transform(const float* __restrict__ x1,
                                                      const float* __restrict__ W2l, const float* __restrict__ b2l,
                                                      const float* __restrict__ W2r, const float* __restrict__ b2r,
                                                      unsigned short* __restrict__ hlb, float* __restrict__ hr, int N) {
    __shared__ float xs[64 * 68];   // row stride 68: per-wave broadcast rows hit banks {0,4,8,12}
    int t = threadIdx.x;
    int node0 = blockIdx.x * 64;
    int nrem = N - node0; if (nrem > 64) nrem = 64;
    const float4* xg = (const float4*)x1;
#pragma unroll
    for (int it = 0; it < 4; ++it) {
        int id = it * 256 + t;
        int row = id >> 4, c4 = id & 15;
        float4 v = make_float4(0.f, 0.f, 0.f, 0.f);
        if (row < nrem) v = xg[(size_t)(node0 + row) * 16 + c4];
        *(float4*)&xs[row * 68 + c4 * 4] = v;
    }
    __syncthreads();
    int nt = t >> 4;
    int jt = t & 15;
    int jq = jt & 7;
    int jc = jq * 4;
    const float4* W4 = (const float4*)((jt < 8) ? W2l : W2r);
    const float4* B4 = (const float4*)((jt < 8) ? b2l : b2r);
    float4 bb = B4[jq];
    float4 acc[4];
#pragma unroll
    for (int i = 0; i < 4; ++i) acc[i] = bb;
#pragma unroll 2
    for (int k4 = 0; k4 < 16; ++k4) {
        float4 w0 = W4[(k4 * 4 + 0) * 8 + jq];
        float4 w1 = W4[(k4 * 4 + 1) * 8 + jq];
        float4 w2 = W4[(k4 * 4 + 2) * 8 + jq];
        float4 w3 = W4[(k4 * 4 + 3) * 8 + jq];
#pragma unroll
        for (int i = 0; i < 4; ++i) {
            float4 xv = *(const float4*)&xs[(nt + i * 16) * 68 + k4 * 4];
            acc[i].x += xv.x * w0.x + xv.y * w1.x + xv.z * w2.x + xv.w * w3.x;
            acc[i].y += xv.x * w0.y + xv.y * w1.y + xv.z * w2.y + xv.w * w3.y;
            acc[i].z += xv.x * w0.z + xv.y * w1.z + xv.z * w2.z + xv.w * w3.z;
            acc[i].w += xv.x * w0.w + xv.y * w1.w + xv.z * w2.w + xv.w * w3.w;
        }
    }
#pragma unroll
    for (int i = 0; i < 4; ++i) {
        int row = nt + i * 16;
        if (row < nrem) {
            size_t node = node0 + row;
            if (jt < 8) {
                uint2 p;
                p.x = (unsigned)f2us(acc[i].x) | ((unsigned)f2us(acc[i].y) << 16);
                p.y = (unsigned)f2us(acc[i].z) | ((unsigned)f2us(acc[i].w) << 16);
                *(uint2*)&hlb[node * 32 + jc] = p;
            } else {
                *(float4*)&hr[node * 32 + jc] = acc[i];
            }
        }
    }
}

// Edge-parallel: 16 lanes per node, lane = edge slot. Full 64B hl row per edge (4x uint4),
// both head logits computed in-register (zero per-edge shfl); one butterfly per node.
__global__ __launch_bounds__(256) void k_l2_agg(const unsigned short* __restrict__ hlb, const float* __restrict__ hr,
                                                const float* __restrict__ att2, const float* __restrict__ b2,
                                                const int2* __restrict__ off2, const int* __restrict__ csr,
                                                float* __restrict__ x2, int N) {
    int tid = threadIdx.x;
    int node = blockIdx.x * 16 + (tid >> 4);
    if (node >= N) return;
    int sl = tid & 15;

    float hrd[32];
    {
        const float4* hr4 = (const float4*)(hr + (size_t)node * 32);
#pragma unroll
        for (int q = 0; q < 8; ++q) {
            float4 v = hr4[q];
            hrd[4 * q + 0] = v.x; hrd[4 * q + 1] = v.y;
            hrd[4 * q + 2] = v.z; hrd[4 * q + 3] = v.w;
        }
    }

    float accA[16], accB[16];
#pragma unroll
    for (int i = 0; i < 16; ++i) { accA[i] = 0.f; accB[i] = 0.f; }
    float den0 = 0.f, den1 = 0.f;

    int2 ee = off2[node];
    int e0 = ee.x, e1 = ee.y;
    for (int jj = e0 + sl; jj < e1; jj += 16) {
        int s = csr[jj];
        const uint4* hp = (const uint4*)(hlb + (size_t)s * 32);
        uint4 u0 = hp[0], u1 = hp[1], u2 = hp[2], u3 = hp[3];
        unsigned int uu[16] = {u0.x, u0.y, u0.z, u0.w, u1.x, u1.y, u1.z, u1.w,
                               u2.x, u2.y, u2.z, u2.w, u3.x, u3.y, u3.z, u3.w};
        float t0 = 0.f, t1 = 0.f;
#pragma unroll
        for (int q = 0; q < 8; ++q) {
            float lo = __uint_as_float(uu[q] << 16);
            float hi = __uint_as_float(uu[q] & 0xFFFF0000u);
            float el = lo + hrd[2 * q];     el = fmaxf(el, 0.2f * el);
            float eh = hi + hrd[2 * q + 1]; eh = fmaxf(eh, 0.2f * eh);
            t0 += att2[2 * q] * el + att2[2 * q + 1] * eh;
        }
#pragma unroll
        for (int q = 8; q < 16; ++q) {
            float lo = __uint_as_float(uu[q] << 16);
            float hi = __uint_as_float(uu[q] & 0xFFFF0000u);
            float el = lo + hrd[2 * q];     el = fmaxf(el, 0.2f * el);
            float eh = hi + hrd[2 * q + 1]; eh = fmaxf(eh, 0.2f * eh);
            t1 += att2[2 * q] * el + att2[2 * q + 1] * eh;
        }
        float w0 = __expf(t0), w1 = __expf(t1);
        den0 += w0; den1 += w1;
#pragma unroll
        for (int q = 0; q < 8; ++q) {
            accA[2 * q]     += w0 * __uint_as_float(uu[q] << 16);
            accA[2 * q + 1] += w0 * __uint_as_float(uu[q] & 0xFFFF0000u);
        }
#pragma unroll
        for (int q = 8; q < 16; ++q) {
            accB[2 * (q - 8)]     += w1 * __uint_as_float(uu[q] << 16);
            accB[2 * (q - 8) + 1] += w1 * __uint_as_float(uu[q] & 0xFFFF0000u);
        }
    }

#pragma unroll
    for (int d = 8; d >= 1; d >>= 1) {
#pragma unroll
        for (int i = 0; i < 16; ++i) {
            if (i < d) {
                { float a = accA[i], b = accA[i + d];
                  float send = (sl & d) ? a : b;
                  float recv = __shfl_xor(send, d);
                  accA[i] = ((sl & d) ? b : a) + recv; }
                { float a = accB[i], b = accB[i + d];
                  float send = (sl & d) ? a : b;
                  float recv = __shfl_xor(send, d);
                  accB[i] = ((sl & d) ? b : a) + recv; }
            }
        }
        den0 += __shfl_xor(den0, d);
        den1 += __shfl_xor(den1, d);
    }
    float sumA = accA[0];
    float sumB = accB[0];

    // self-loop (cooperative: lane sl holds channels sl and 16+sl)
    float hr0 = hr[(size_t)node * 32 + sl];
    float hr1 = hr[(size_t)node * 32 + 16 + sl];
    float hl0 = us2f(hlb[(size_t)node * 32 + sl]);
    float hl1 = us2f(hlb[(size_t)node * 32 + 16 + sl]);
    float ea = hl0 + hr0; ea = fmaxf(ea, 0.2f * ea);
    float eb = hl1 + hr1; eb = fmaxf(eb, 0.2f * eb);
    float p0 = att2[sl] * ea;
    float p1 = att2[16 + sl] * eb;
    p0 += __shfl_xor(p0, 1); p0 += __shfl_xor(p0, 2); p0 += __shfl_xor(p0, 4); p0 += __shfl_xor(p0, 8);
    p1 += __shfl_xor(p1, 1); p1 += __shfl_xor(p1, 2); p1 += __shfl_xor(p1, 4); p1 += __shfl_xor(p1, 8);
    float w0 = __expf(p0), w1 = __expf(p1);
    sumA += w0 * hl0; den0 += w0;
    sumB += w1 * hl1; den1 += w1;

    x2[(size_t)node * 32 + sl]      = sumA / (den0 + 1e-16f) + b2[sl];
    x2[(size_t)node * 32 + 16 + sl] = sumB / (den1 + 1e-16f) + b2[16 + sl];
}

// ---------------- Layer 3: TransformerConv(32, 7, heads=1) ----------------

// 128 nodes per 256-thread block; thread = 4-node x 4-col tile.
// Cols jt<4 -> QS (f32); jt>=4 -> KVb (bf16-packed 32B row = {K0..6,0,V0..6,0}).
__global__ __launch_bounds__(256) void k_l3_transform(const float* __restrict__ x2,
                                                      const float4* __restrict__ Wc4, const float4* __restrict__ bc4,
                                                      float* __restrict__ QS, unsigned short* __restrict__ KVb, int N) {
    __shared__ float xs[128 * 36];
    int t = threadIdx.x;
    int node0 = blockIdx.x * 128;
    int nrem = N - node0; if (nrem > 128) nrem = 128;
    const float4* xg = (const float4*)x2;
#pragma unroll
    for (int it = 0; it < 4; ++it) {
        int id = it * 256 + t;
        int row = id >> 3, c4 = id & 7;
        float4 v = make_float4(0.f, 0.f, 0.f, 0.f);
        if (row < nrem) v = xg[(size_t)(node0 + row) * 8 + c4];
        *(float4*)&xs[row * 36 + c4 * 4] = v;
    }
    __syncthreads();
    int nt = t >> 3;
    int jt = t & 7;
    float4 bb = bc4[jt];
    float4 acc[4];
#pragma unroll
    for (int i = 0; i < 4; ++i) acc[i] = bb;
#pragma unroll 2
    for (int k4 = 0; k4 < 8; ++k4) {
        float4 w0 = Wc4[(k4 * 4 + 0) * 8 + jt];
        float4 w1 = Wc4[(k4 * 4 + 1) * 8 + jt];
        float4 w2 = Wc4[(k4 * 4 + 2) * 8 + jt];
        float4 w3 = Wc4[(k4 * 4 + 3) * 8 + jt];
#pragma unroll
        for (int i = 0; i < 4; ++i) {
            float4 xv = *(const float4*)&xs[(nt + i * 32) * 36 + k4 * 4];
            acc[i].x += xv.x * w0.x + xv.y * w1.x + xv.z * w2.x + xv.w * w3.x;
            acc[i].y += xv.x * w0.y + xv.y * w1.y + xv.z * w2.y + xv.w * w3.y;
            acc[i].z += xv.x * w0.z + xv.y * w1.z + xv.z * w2.z + xv.w * w3.z;
            acc[i].w += xv.x * w0.w + xv.y * w1.w + xv.z * w2.w + xv.w * w3.w;
        }
    }
#pragma unroll
    for (int i = 0; i < 4; ++i) {
        int row = nt + i * 32;
        if (row < nrem) {
            size_t node = node0 + row;
            if (jt < 4) {
                *(float4*)(QS + node * 16 + jt * 4) = acc[i];
            } else {
                uint2 p;
                p.x = (unsigned)f2us(acc[i].x) | ((unsigned)f2us(acc[i].y) << 16);
                p.y = (unsigned)f2us(acc[i].z) | ((unsigned)f2us(acc[i].w) << 16);
                *(uint2*)&KVb[node * 16 + (size_t)(jt - 4) * 4] = p;
            }
        }
    }
}

// Edge-parallel: 8 lanes per node, lane = edge slot; bf16 K|V row per edge (2x uint4 = 32B,
// KVb table 3.2MB -> per-XCD L2-resident); dot in f32; 8 values (7 acc + den) butterflied.
__global__ __launch_bounds__(256) void k_l3_agg(const float* __restrict__ QS, const unsigned short* __restrict__ KVb,
                                                const int2* __restrict__ off2, const int* __restrict__ csr,
                                                float* __restrict__ out, int N) {
    int tid = threadIdx.x;
    int node = blockIdx.x * 32 + (tid >> 3);
    if (node >= N) return;
    int sl = tid & 7;
    int lane = tid & 63;
    const float scale = 0.3779644730092272f;  // 1/sqrt(7)
    const float4* q4 = (const float4*)(QS + (size_t)node * 16);
    float4 qa = q4[0], qb = q4[1];
    qa.x *= scale; qa.y *= scale; qa.z *= scale; qa.w *= scale;
    qb.x *= scale; qb.y *= scale; qb.z *= scale; qb.w = 0.f;

    float v[8];
#pragma unroll
    for (int i = 0; i < 8; ++i) v[i] = 0.f;

    int2 ee = off2[node];
    int e0 = ee.x, e1 = ee.y;
    for (int jj = e0 + sl; jj < e1; jj += 8) {
        int s = csr[jj];
        const uint4* kp = (const uint4*)(KVb + (size_t)s * 16);
        uint4 uk = kp[0], uv = kp[1];
        float k0 = __uint_as_float(uk.x << 16),        k1 = __uint_as_float(uk.x & 0xFFFF0000u);
        float k2 = __uint_as_float(uk.y << 16),        k3 = __uint_as_float(uk.y & 0xFFFF0000u);
        float k4 = __uint_as_float(uk.z << 16),        k5 = __uint_as_float(uk.z & 0xFFFF0000u);
        float k6 = __uint_as_float(uk.w << 16);
        float t = qa.x * k0 + qa.y * k1 + qa.z * k2 + qa.w * k3
                + qb.x * k4 + qb.y * k5 + qb.z * k6;
        float w = __expf(t);
        v[0] += w * __uint_as_float(uv.x << 16);
        v[1] += w * __uint_as_float(uv.x & 0xFFFF0000u);
        v[2] += w * __uint_as_float(uv.y << 16);
        v[3] += w * __uint_as_float(uv.y & 0xFFFF0000u);
        v[4] += w * __uint_as_float(uv.z << 16);
        v[5] += w * __uint_as_float(uv.z & 0xFFFF0000u);
        v[6] += w * __uint_as_float(uv.w << 16);
        v[7] += w;
    }
#pragma unroll
    for (int d = 4; d >= 1; d >>= 1) {
#pragma unroll
        for (int i = 0; i < 8; ++i) {
            if (i < d) {
                float a = v[i], b = v[i + d];
                float send = (sl & d) ? a : b;
                float recv = __shfl_xor(send, d);
                v[i] = ((sl & d) ? b : a) + recv;
            }
        }
    }
    float r = v[0];
    float den = __shfl(r, (lane & 56) + 7);
    if (sl < 7) out[(size_t)node * 7 + sl] = r / (den + 1e-16f)
                                             + QS[(size_t)node * 16 + 8 + sl];
}

// ---------------- launcher ----------------

extern "C" void kernel_launch(void* const* d_in, const int* in_sizes, int n_in,
                              void* d_out, int out_size, void* d_ws, size_t ws_size,
                              hipStream_t stream) {
    const int* ei = (const int*)d_in[1];
    float* out = (float*)d_out;

    int N = in_sizes[0] / 3;
    int E = in_sizes[1] / 2;
    int NB = (N + 1023) >> 10;   // assumed <= 256 (N <= 262144)
    int C = (E + NB - 1) / NB + 4096;   // fixed bucket capacity (mean + huge slack for random dst)

    char* ws = (char*)d_ws;
    size_t o = 0;
    auto take = [&](size_t bytes) -> char* {
        char* p = ws + o;
        o = (o + bytes + 255) & ~(size_t)255;
        return p;
    };
    int total_f = 0;
    for (int i = 0; i < 20; ++i) if (i != 1) total_f += in_sizes[i];
    float* canon   = (float*)take((size_t)total_f * 4);
    float* Wcat    = (float*)take(32 * 32 * 4);
    float* bcat    = (float*)take(32 * 4);
    int2*  off2    = (int2*)take((size_t)N * 8);
    int*   bcur    = (int*)take(256 * 4);
    int*   csr     = (int*)take((size_t)NB * C * 4);
    float* bufA    = (float*)take((size_t)N * 64 * 4);  // x4 -> hlb|hr -> QS|KVb
    float* as1     = (float*)take((size_t)N * 4 * 4);
    float* ad1     = (float*)take((size_t)N * 4 * 4);
    float* bufB    = (float*)take((size_t)N * 64 * 4);  // bkt -> x1 -> x2
    (void)ws_size; (void)n_in; (void)out_size;

    CvtArgs ca;
    const float* cp[20];
    {
        int off_ = 0, k = 0;
        for (int i = 0; i < 20; ++i) {
            if (i == 1) { cp[i] = nullptr; continue; }
            ca.p[k] = d_in[i];
            ca.sz[k] = in_sizes[i];
            cp[i] = canon + off_;
            off_ += in_sizes[i];
            ++k;
        }
    }

    int nbconv = (total_f + 255) / 256;
    k_convert<<<nbconv + 1, 256, 0, stream>>>(ca, canon, total_f, nbconv, Wcat, bcat, bcur);

    // bkt aliases bufB (NB*C*4 B ~= 8 MB <= N*256 B); x1 written only after k_bbuild
    int* bkt = (int*)bufB;
    int gb = (E + 4095) / 4096;
    k_bscatter<<<gb, 1024, 0, stream>>>(ei, bcur, bkt, E, NB, C);
    k_bbuild<<<NB, 1024, 0, stream>>>(bkt, bcur, off2, csr, N, C);

    float4* x4 = (float4*)bufA;                                  // N*16B = 1.6 MB, L2-resident
    k_l1_transform<<<(N + 3) / 4, 256, 0, stream>>>(cp[0], cp[2], cp[3], cp[4], x4, as1, ad1, N);
    float* x1 = bufB;
    k_l1_agg<<<(N + 15) / 16, 256, 0, stream>>>(x4, (const float4*)as1, (const float4*)ad1,
                                                off2, csr, cp[2], cp[5], x1, N);

    unsigned short* hlb = (unsigned short*)bufA;                 // N*32 bf16 = 6.4 MB
    float* hr = bufA + (size_t)N * 16;
    k_l2_transform<<<(N + 63) / 64, 256, 0, stream>>>(x1, cp[6], cp[7], cp[8], cp[9], hlb, hr, N);
    float* x2 = bufB;
    k_l2_agg<<<(N + 15) / 16, 256, 0, stream>>>(hlb, hr, cp[10], cp[11], off2, csr, x2, N);

    float* QS = bufA;                                            // N*16 floats
    unsigned short* KVb = (unsigned short*)(bufA + (size_t)N * 16);  // N*16 bf16 = 3.2 MB (L2-resident)
    k_l3_transform<<<(N + 127) / 128, 256, 0, stream>>>(x2, (const float4*)Wcat, (const float4*)bcat,
                                                        QS, KVb, N);
    k_l3_agg<<<(N + 31) / 32, 256, 0, stream>>>(QS, KVb, off2, csr, out, N);
}